// Round 4
// baseline (195.172 us; speedup 1.0000x reference)
//
#include <hip/hip_runtime.h>

#define Dm 96
#define PL (Dm*Dm*Dm)               // 884736 elements per (b, ic) plane
#define ICn 16
#define OCn 16
#define HYPn 128
#define BSn 4
// K-packing: 15 groups of K=32. group grp = ty*5 + g (ty = ky tap 0..2, g = 0..4).
// Within a group: k_local = cl*16 + ic, cl in {0,1} -> (kz,kx) combo c = 2g+cl
// (c = kz*3 + kx; c = 9 is zero padding). Single ky per group => B-fragment value
// depends only on the INPUT y-plane, shared across neighboring output rows.
#define NG 15
#define FRAG_ELEMS (NG*64*8)        // 7680 bf16 per sample (A fragments in lane order)

typedef float   f32x4  __attribute__((ext_vector_type(4)));
typedef __bf16  bf16x8 __attribute__((ext_vector_type(8)));

__device__ __forceinline__ unsigned short f2bf(float f) {
    unsigned u = __builtin_bit_cast(unsigned, f);
    u = (u + 0x7FFFu + ((u >> 16) & 1u)) >> 16;
    return (unsigned short)u;
}

// ---------------- hypernetwork: A-fragments in MFMA lane order ----------------
// kwf[((b*NG + grp)*64 + lane)*8 + j]:
//   oc = lane&15, hi = lane>>4, k_local = hi*8 + j = cl*16 + ic
//   ty = grp/5, c = 2*(grp%5) + cl; c<9 -> weight W[b][oc][ic][kz=c/3][ky=ty][kx=c%3]
__global__ __launch_bounds__(256)
void hyper_frag_kernel(const float* __restrict__ hyp, const float* __restrict__ Wk,
                       const float* __restrict__ bk, unsigned short* __restrict__ kwf)
{
    int t = blockIdx.x * 256 + threadIdx.x;
    if (t >= BSn * FRAG_ELEMS) return;
    int j    = t & 7;
    int lane = (t >> 3) & 63;
    int rest = t >> 9;
    int grp  = rest % NG;
    int b    = rest / NG;
    int oc = lane & 15, hi = lane >> 4;
    int ty = grp / 5, g = grp % 5;
    int cl = hi >> 1;
    int ic = (hi & 1) * 8 + j;
    int c  = 2 * g + cl;
    float acc = 0.f;
    if (c < 9) {
        int tz = c / 3, tx = c % 3;
        int r = (oc * ICn + ic) * 27 + (tz * 9 + ty * 3 + tx);
        const float4* w = (const float4*)(Wk + (long)r * HYPn);
        const float4* h = (const float4*)(hyp + (long)b * HYPn);
        acc = bk[r];
#pragma unroll
        for (int q = 0; q < HYPn / 4; ++q) {
            float4 a = h[q], cc = w[q];
            acc += a.x * cc.x + a.y * cc.y + a.z * cc.z + a.w * cc.w;
        }
    }
    kwf[t] = f2bf(acc);
}

__global__ __launch_bounds__(64)
void hyper_bias_kernel(const float* __restrict__ hyp, const float* __restrict__ Wb,
                       const float* __restrict__ bb, float* __restrict__ bias)
{
    int t = threadIdx.x;          // 64 = 4 samples * 16 oc
    int b = t >> 4, oc = t & 15;
    const float4* w = (const float4*)(Wb + (long)oc * HYPn);
    const float4* h = (const float4*)(hyp + (long)b * HYPn);
    float acc = bb[oc];
#pragma unroll
    for (int q = 0; q < HYPn / 4; ++q) {
        float4 a = h[q], c = w[q];
        acc += a.x * c.x + a.y * c.y + a.z * c.z + a.w * c.w;
    }
    bias[t] = acc;                // [b][oc]
}

// ---------------- MFMA implicit-GEMM conv ----------------
// Block tile: 16 oc x (4z x 8y x 16x). 512 threads = 8 waves: wave = (wz, wh),
// wz = z offset 0..3, wh = y-half; each wave computes 4 y-rows via 6 input planes.
// LDS x tile: [6z][10y][18x] spatial points, 48B stride (32B = 16 ic bf16 + 16B pad).
#define ZT 4
#define YT 8
#define XT 16
#define ZL 6
#define YL 10
#define XL 18
#define SPN (ZL*YL*XL)              // 1080 spatial points
#define SSTR 48                     // bytes per spatial point
#define LDSB (SPN*SSTR)             // 51840 bytes

__device__ constexpr int coff(int c) {   // (kz,kx) combo byte offset within the tile
    return ((c / 3) * YL * XL + (c % 3)) * SSTR;
}

__global__ __launch_bounds__(512, 4)
void conv_mfma_kernel(const float* __restrict__ x, const unsigned short* __restrict__ kwf,
                      const float* __restrict__ bias, float* __restrict__ out)
{
    __shared__ __align__(16) char smem[LDSB];

    const int NXT = Dm / XT, NYT = Dm / YT, NZT = Dm / ZT;    // 6, 12, 24
    // XCD-aware bijective swizzle (6912 % 8 == 0)
    int raw = blockIdx.x;
    int bid = (raw & 7) * ((BSn * NXT * NYT * NZT) / 8) + (raw >> 3);

    int txi = bid % NXT; bid /= NXT;
    int tyi = bid % NYT; bid /= NYT;
    int tzi = bid % NZT;
    int b   = bid / NZT;
    int x0 = txi * XT, y0 = tyi * YT, z0 = tzi * ZT;

    int tid  = threadIdx.x;
    int lane = tid & 63;
    int wave = tid >> 6;
    int wz   = wave & 3;             // z offset of this wave
    int wh   = wave >> 2;            // y-half (0 -> rows 0..3, 1 -> rows 4..7)

    const float* xb = x + (long)b * ICn * PL;

    // ---- load A fragments (this sample's weights; L2-resident) ----
    const unsigned short* kwb = kwf + (long)b * FRAG_ELEMS;
    bf16x8 afr[NG];
#pragma unroll
    for (int grp = 0; grp < NG; ++grp)
        afr[grp] = *(const bf16x8*)(kwb + (grp * 64 + lane) * 8);

    // ---- stage x tile: one task = one (z,y,x) point x 8 ic's -> 1 ds_write_b128 ----
    for (int t = tid; t < 2 * SPN; t += 512) {
        int ich = (t >= SPN) ? 1 : 0;
        int sp  = t - ich * SPN;
        int lx = sp % XL;
        int r  = sp / XL;
        int ly = r % YL;
        int lz = r / YL;
        int gz = z0 - 1 + lz, gy = y0 - 1 + ly, gx = x0 - 1 + lx;
        bf16x8 vv;
        if ((unsigned)gz < (unsigned)Dm && (unsigned)gy < (unsigned)Dm &&
            (unsigned)gx < (unsigned)Dm) {
            const float* g = xb + (long)(ich * 8) * PL + ((long)gz * Dm + gy) * Dm + gx;
#pragma unroll
            for (int q = 0; q < 8; ++q) vv[q] = (__bf16)g[(long)q * PL];
        } else {
#pragma unroll
            for (int q = 0; q < 8; ++q) vv[q] = (__bf16)0.f;
        }
        *(bf16x8*)(smem + sp * SSTR + ich * 16) = vv;
    }

    __syncthreads();

    int n   = lane & 15;             // spatial column (x offset)
    int hi  = lane >> 4;
    int cl  = hi >> 1;               // (kz,kx)-combo select within group
    int ich = hi & 1;                // ic half

    // per-lane base address for each g (plane offset added as compile-time imm)
    int addr_g[5];
#pragma unroll
    for (int g = 0; g < 5; ++g) {
        int c = 2 * g + cl;
        if (c > 8) c = 8;            // pad combo -> safe addr (A is zero there)
        addr_g[g] = ((wz * YL + 4 * wh) * XL + n) * SSTR + ich * 16 + coff(c);
    }

    f32x4 acc[4];
#pragma unroll
    for (int yy = 0; yy < 4; ++yy) acc[yy] = (f32x4){0.f, 0.f, 0.f, 0.f};

    // 6 input planes feed 4 output rows; each plane read once, used by up to 3 rows
#pragma unroll
    for (int p = 0; p < 6; ++p) {
        bf16x8 F[5];
#pragma unroll
        for (int g = 0; g < 5; ++g)
            F[g] = *(const bf16x8*)(smem + addr_g[g] + p * (XL * SSTR));
#pragma unroll
        for (int ty = 0; ty < 3; ++ty) {
            int yy = p - ty;
            if (yy >= 0 && yy < 4) {
#pragma unroll
                for (int g = 0; g < 5; ++g)
                    acc[yy] = __builtin_amdgcn_mfma_f32_16x16x32_bf16(
                        afr[ty * 5 + g], F[g], acc[yy], 0, 0, 0);
            }
        }
    }

    // epilogue
    float4 bv = *(const float4*)(bias + b * OCn + hi * 4);
    int zo = z0 + wz;
#pragma unroll
    for (int yy = 0; yy < 4; ++yy) {
        int yo = y0 + 4 * wh + yy;
        long obase = ((((long)b * OCn + hi * 4) * Dm + zo) * Dm + yo) * Dm + x0 + n;
#pragma unroll
        for (int r = 0; r < 4; ++r)
            out[obase + (long)r * PL] = acc[yy][r] + ((const float*)&bv)[r];
    }
}

extern "C" void kernel_launch(void* const* d_in, const int* in_sizes, int n_in,
                              void* d_out, int out_size, void* d_ws, size_t ws_size,
                              hipStream_t stream)
{
    const float* x   = (const float*)d_in[0];
    const float* hyp = (const float*)d_in[1];
    const float* Wk  = (const float*)d_in[2];
    const float* bk  = (const float*)d_in[3];
    const float* Wb  = (const float*)d_in[4];
    const float* bb  = (const float*)d_in[5];
    float* out = (float*)d_out;

    unsigned short* kwf = (unsigned short*)d_ws;                        // 61440 B
    float* bias = (float*)((char*)d_ws + (size_t)BSn * FRAG_ELEMS * 2); // 64 floats

    hipLaunchKernelGGL(hyper_frag_kernel, dim3((BSn * FRAG_ELEMS) / 256), dim3(256), 0, stream,
                       hyp, Wk, bk, kwf);
    hipLaunchKernelGGL(hyper_bias_kernel, dim3(1), dim3(64), 0, stream,
                       hyp, Wb, bb, bias);

    const int nblk = BSn * (Dm / XT) * (Dm / YT) * (Dm / ZT);           // 6912
    hipLaunchKernelGGL(conv_mfma_kernel, dim3(nblk), dim3(512), 0, stream,
                       x, kwf, bias, out);
}

// Round 5
// 190.015 us; speedup vs baseline: 1.0271x; 1.0271x over previous
//
#include <hip/hip_runtime.h>

#define Dm 96
#define PL (Dm*Dm*Dm)               // 884736 elements per (b, ic) plane
#define ICn 16
#define OCn 16
#define HYPn 128
#define BSn 4
// K-packing: 15 groups of K=32. grp = ty*5 + g (ty = ky tap 0..2, g = 0..4).
// k_local = cl*16 + ic, cl in {0,1} -> (kz,kx) combo c = 2g+cl (c=9 is padding).
// Single ky per group => B-fragment depends only on the INPUT y-plane, shared
// across neighboring output rows.
#define NG 15
#define FRAG_ELEMS (NG*64*8)        // 7680 bf16 per sample

typedef float   f32x4  __attribute__((ext_vector_type(4)));
typedef float   f32x2  __attribute__((ext_vector_type(2)));
typedef __bf16  bf16x8 __attribute__((ext_vector_type(8)));

__device__ __forceinline__ unsigned short f2bf(float f) {
    unsigned u = __builtin_bit_cast(unsigned, f);
    u = (u + 0x7FFFu + ((u >> 16) & 1u)) >> 16;
    return (unsigned short)u;
}

// ---------------- hypernetwork: A-fragments in MFMA lane order ----------------
__global__ __launch_bounds__(256)
void hyper_frag_kernel(const float* __restrict__ hyp, const float* __restrict__ Wk,
                       const float* __restrict__ bk, unsigned short* __restrict__ kwf)
{
    int t = blockIdx.x * 256 + threadIdx.x;
    if (t >= BSn * FRAG_ELEMS) return;
    int j    = t & 7;
    int lane = (t >> 3) & 63;
    int rest = t >> 9;
    int grp  = rest % NG;
    int b    = rest / NG;
    int oc = lane & 15, hi = lane >> 4;
    int ty = grp / 5, g = grp % 5;
    int cl = hi >> 1;
    int ic = (hi & 1) * 8 + j;
    int c  = 2 * g + cl;
    float acc = 0.f;
    if (c < 9) {
        int tz = c / 3, tx = c % 3;
        int r = (oc * ICn + ic) * 27 + (tz * 9 + ty * 3 + tx);
        const float4* w = (const float4*)(Wk + (long)r * HYPn);
        const float4* h = (const float4*)(hyp + (long)b * HYPn);
        acc = bk[r];
#pragma unroll
        for (int q = 0; q < HYPn / 4; ++q) {
            float4 a = h[q], cc = w[q];
            acc += a.x * cc.x + a.y * cc.y + a.z * cc.z + a.w * cc.w;
        }
    }
    kwf[t] = f2bf(acc);
}

__global__ __launch_bounds__(64)
void hyper_bias_kernel(const float* __restrict__ hyp, const float* __restrict__ Wb,
                       const float* __restrict__ bb, float* __restrict__ bias)
{
    int t = threadIdx.x;          // 64 = 4 samples * 16 oc
    int b = t >> 4, oc = t & 15;
    const float4* w = (const float4*)(Wb + (long)oc * HYPn);
    const float4* h = (const float4*)(hyp + (long)b * HYPn);
    float acc = bb[oc];
#pragma unroll
    for (int q = 0; q < HYPn / 4; ++q) {
        float4 a = h[q], c = w[q];
        acc += a.x * c.x + a.y * c.y + a.z * c.z + a.w * c.w;
    }
    bias[t] = acc;                // [b][oc]
}

// ---------------- MFMA implicit-GEMM conv ----------------
// Block tile: 16 oc x (4z x 8y x 16x). 256 threads = 4 waves, wave = z-row,
// each wave computes 8 y-rows from 10 input planes (B-fragment shared over y).
// LDS x tile: [6z][10y][18x] points, 48B stride (32B data + 16B pad; 3 granules
// per point, gcd(3,8)=1 -> conflict-free b128 access).
#define ZT 4
#define YT 8
#define XT 16
#define ZL 6
#define YL 10
#define XL 18
#define SPN (ZL*YL*XL)              // 1080 spatial points
#define SSTR 48
#define LDSB (SPN*SSTR)             // 51840 bytes

__device__ constexpr int coff(int c) {   // (kz,kx) combo byte offset
    return ((c / 3) * YL * XL + (c % 3)) * SSTR;
}

__global__ __launch_bounds__(256, 3)
void conv_mfma_kernel(const float* __restrict__ x, const unsigned short* __restrict__ kwf,
                      const float* __restrict__ bias, float* __restrict__ out)
{
    __shared__ __align__(16) char smem[LDSB];

    const int NXT = Dm / XT, NYT = Dm / YT, NZT = Dm / ZT;    // 6, 12, 24
    int raw = blockIdx.x;
    int bid = (raw & 7) * ((BSn * NXT * NYT * NZT) / 8) + (raw >> 3);

    int txi = bid % NXT; bid /= NXT;
    int tyi = bid % NYT; bid /= NYT;
    int tzi = bid % NZT;
    int b   = bid / NZT;
    int x0 = txi * XT, y0 = tyi * YT, z0 = tzi * ZT;

    int tid  = threadIdx.x;
    int lane = tid & 63;
    int wz   = tid >> 6;             // wave -> z-row (0..3)

    const float* xb = x + (long)b * ICn * PL;

    // ---- staging, pair tasks: 960 = 8 x-pairs * 2 ic-halves * 60 rows ----
    // 8 lanes * float2 = one aligned 64B line (x0..x0+15) per (row, ic).
    for (int t = tid; t < 960; t += 256) {
        int pt  = t & 7;
        int ich = (t >> 3) & 1;
        int row = t >> 4;                    // 0..59
        int ly = row % YL, lz = row / YL;
        int gz = z0 - 1 + lz, gy = y0 - 1 + ly;
        int gx = x0 + 2 * pt;                // even -> 8B aligned
        bf16x8 v0, v1;
        if ((unsigned)gz < (unsigned)Dm && (unsigned)gy < (unsigned)Dm) {
            const float* g = xb + (long)(ich * 8) * PL + ((long)gz * Dm + gy) * Dm + gx;
#pragma unroll
            for (int q = 0; q < 8; ++q) {
                f32x2 p = *(const f32x2*)(g + (long)q * PL);
                v0[q] = (__bf16)p.x;
                v1[q] = (__bf16)p.y;
            }
        } else {
#pragma unroll
            for (int q = 0; q < 8; ++q) { v0[q] = (__bf16)0.f; v1[q] = (__bf16)0.f; }
        }
        int sp = (lz * YL + ly) * XL + (1 + 2 * pt);
        *(bf16x8*)(smem + sp * SSTR + ich * 16)          = v0;
        *(bf16x8*)(smem + (sp + 1) * SSTR + ich * 16)    = v1;
    }
    // halo singles: 240 = 2 sides * 2 ic-halves * 60 rows
    for (int t = tid; t < 240; t += 256) {
        int s   = t & 1;
        int ich = (t >> 1) & 1;
        int row = t >> 2;
        int ly = row % YL, lz = row / YL;
        int gz = z0 - 1 + lz, gy = y0 - 1 + ly;
        int lx = s ? (XL - 1) : 0;
        int gx = x0 - 1 + lx;
        bf16x8 v;
        if ((unsigned)gz < (unsigned)Dm && (unsigned)gy < (unsigned)Dm &&
            (unsigned)gx < (unsigned)Dm) {
            const float* g = xb + (long)(ich * 8) * PL + ((long)gz * Dm + gy) * Dm + gx;
#pragma unroll
            for (int q = 0; q < 8; ++q) v[q] = (__bf16)g[(long)q * PL];
        } else {
#pragma unroll
            for (int q = 0; q < 8; ++q) v[q] = (__bf16)0.f;
        }
        int sp = (lz * YL + ly) * XL + lx;
        *(bf16x8*)(smem + sp * SSTR + ich * 16) = v;
    }

    // ---- A fragments: load once, pin in VGPRs (prevent rematerialization) ----
    const unsigned short* kwb = kwf + (long)b * FRAG_ELEMS;
    f32x4 afr[NG];
#pragma unroll
    for (int grp = 0; grp < NG; ++grp) {
        afr[grp] = *(const f32x4*)(kwb + (grp * 64 + lane) * 8);
        asm volatile("" : "+v"(afr[grp]));
    }

    __syncthreads();

    int n   = lane & 15;
    int hi  = lane >> 4;
    int cl  = hi >> 1;
    int ich = hi & 1;

    int addr_g[5];
#pragma unroll
    for (int g = 0; g < 5; ++g) {
        int c = 2 * g + cl;
        if (c > 8) c = 8;                    // pad combo -> safe addr (A is zero)
        addr_g[g] = ((wz * YL) * XL + n) * SSTR + ich * 16 + coff(c);
    }

    f32x4 acc[YT];
#pragma unroll
    for (int yy = 0; yy < YT; ++yy) acc[yy] = (f32x4){0.f, 0.f, 0.f, 0.f};

    // 10 input planes feed 8 output rows; each plane read once per combo-set
#pragma unroll
    for (int p = 0; p < YL; ++p) {
        bf16x8 F[5];
#pragma unroll
        for (int g = 0; g < 5; ++g)
            F[g] = *(const bf16x8*)(smem + addr_g[g] + p * (XL * SSTR));
#pragma unroll
        for (int ty = 0; ty < 3; ++ty) {
            int yy = p - ty;
            if (yy >= 0 && yy < YT) {
#pragma unroll
                for (int g = 0; g < 5; ++g)
                    acc[yy] = __builtin_amdgcn_mfma_f32_16x16x32_bf16(
                        __builtin_bit_cast(bf16x8, afr[ty * 5 + g]), F[g], acc[yy], 0, 0, 0);
            }
        }
    }

    // epilogue
    float4 bv = *(const float4*)(bias + b * OCn + hi * 4);
    int zo = z0 + wz;
#pragma unroll
    for (int yy = 0; yy < YT; ++yy) {
        int yo = y0 + yy;
        long obase = ((((long)b * OCn + hi * 4) * Dm + zo) * Dm + yo) * Dm + x0 + n;
#pragma unroll
        for (int r = 0; r < 4; ++r)
            out[obase + (long)r * PL] = acc[yy][r] + ((const float*)&bv)[r];
    }
}

extern "C" void kernel_launch(void* const* d_in, const int* in_sizes, int n_in,
                              void* d_out, int out_size, void* d_ws, size_t ws_size,
                              hipStream_t stream)
{
    const float* x   = (const float*)d_in[0];
    const float* hyp = (const float*)d_in[1];
    const float* Wk  = (const float*)d_in[2];
    const float* bk  = (const float*)d_in[3];
    const float* Wb  = (const float*)d_in[4];
    const float* bb  = (const float*)d_in[5];
    float* out = (float*)d_out;

    unsigned short* kwf = (unsigned short*)d_ws;                        // 61440 B
    float* bias = (float*)((char*)d_ws + (size_t)BSn * FRAG_ELEMS * 2); // 64 floats

    hipLaunchKernelGGL(hyper_frag_kernel, dim3((BSn * FRAG_ELEMS) / 256), dim3(256), 0, stream,
                       hyp, Wk, bk, kwf);
    hipLaunchKernelGGL(hyper_bias_kernel, dim3(1), dim3(64), 0, stream,
                       hyp, Wb, bb, bias);

    const int nblk = BSn * (Dm / XT) * (Dm / YT) * (Dm / ZT);           // 6912
    hipLaunchKernelGGL(conv_mfma_kernel, dim3(nblk), dim3(256), 0, stream,
                       x, kwf, bias, out);
}